// Round 7
// baseline (1093.881 us; speedup 1.0000x reference)
//
#include <hip/hip_runtime.h>

#define SEQ 64

typedef _Float16 f16;
typedef _Float16 f16x8 __attribute__((ext_vector_type(8)));
typedef _Float16 f16x2 __attribute__((ext_vector_type(2)));
typedef float f32x4 __attribute__((ext_vector_type(4)));

__device__ __forceinline__ float sig_(float x) { return 1.0f / (1.0f + __expf(-x)); }
__device__ __forceinline__ float tanh_(float x) { return 1.0f - 2.0f / (1.0f + __expf(2.0f * x)); }

template<int CTRL, int RMASK>
__device__ __forceinline__ float dpp_add(float x) {
  const int t = __builtin_amdgcn_update_dpp(0, __float_as_int(x), CTRL, RMASK, 0xF, true);
  return x + __int_as_float(t);
}
template<int CTRL>
__device__ __forceinline__ float dpp_max(float x) {
  const int t = __builtin_amdgcn_update_dpp(0, __float_as_int(x), CTRL, 0xF, 0xF, true);
  return fmaxf(x, __int_as_float(t));
}

// h state: node-major, 128 f16/row, XOR-swizzled in 8-f16 (16B) blocks
__device__ __forceinline__ int hOff(int n, int f) {
  return n * 128 + ((((f >> 3) ^ (n & 15)) << 3) | (f & 7));
}

// ---- prep: comp_W (256x640 fp32) -> f16 MFMA B-fragment order in ws ----
__global__ void prep_kernel(const float* __restrict__ cW, f16* __restrict__ wsB) {
  const int idx  = blockIdx.x * 256 + threadIdx.x;   // 0..20479
  const int kk   = idx / 2560;
  const int rem  = idx - kk * 2560;
  const int nt   = rem >> 6;
  const int lane = rem & 63;
  const int col  = nt * 16 + (lane & 15);
  const int kb   = kk * 32 + ((lane >> 4) << 3);
  f16x8 v;
  #pragma unroll
  for (int j = 0; j < 8; ++j) v[j] = (f16)cW[(kb + j) * 640 + col];
  ((f16x8*)wsB)[idx] = v;
}

// ---- pyramid: 256 threads (4 waves, 1 wave/SIMD -> 512-reg budget) ----
__global__ __launch_bounds__(256, 1) void pyramid_kernel(
    const int*   __restrict__ sentences,
    const float* __restrict__ emb,
    const f16*   __restrict__ wsB,
    const float* __restrict__ cb, const float* __restrict__ selw, const float* __restrict__ selb,
    float* __restrict__ finT)
{
  __shared__ __align__(16) f16   hS[65 * 128];    // 16640 B
  __shared__ __align__(16) float cS[65 * 132];    // 34320 B
  __shared__ float lgp[8 * 64];                   // 2048 B
  __shared__ __align__(16) float pS[64], clS[64], crS[64];  // 768 B

  const int tid  = threadIdx.x;
  const int b    = blockIdx.x;
  const int wv   = tid >> 6;       // 0..3; owns d-groups 2wv, 2wv+1
  const int lane = tid & 63;
  const int quad = lane >> 4;
  const int l15  = lane & 15;
  const f16x8* Bf = (const f16x8*)wsB;

  // ---- persistent B: 80 frags/wave = 320 regs (arch VGPR + AGPR banks) ----
  f16x8 Breg[8][2][5];   // [kk][dgi][q]
  #pragma unroll
  for (int kk = 0; kk < 8; ++kk)
    #pragma unroll
    for (int dgi = 0; dgi < 2; ++dgi)
      #pragma unroll
      for (int q = 0; q < 5; ++q)
        Breg[kk][dgi][q] = Bf[((kk * 40 + q * 8 + (2 * wv + dgi)) << 6) + lane];

  // ---- embedding gather: h -> LDS f16, c -> LDS f32 ----
  {
    const int s = tid >> 2, part = tid & 3;
    const int row = sentences[b * SEQ + s];
    const float4* er = (const float4*)(emb + (size_t)row * 256 + part * 64);
    #pragma unroll
    for (int i4 = 0; i4 < 16; ++i4) {
      const float4 v = er[i4];
      const float vv[4] = {v.x, v.y, v.z, v.w};
      #pragma unroll
      for (int c = 0; c < 4; ++c) {
        const int f = part * 64 + i4 * 4 + c;
        if (f < 128) hS[hOff(s, f)] = (f16)vv[c];
        else         cS[s * 132 + (f - 128)] = vv[c];
      }
    }
  }
  if (tid < 128) hS[64 * 128 + tid] = (f16)0.f;   // guard row (node 64)
  if (tid < 132) cS[64 * 132 + tid] = 0.f;
  __syncthreads();

  float bq[2][5], swh[2], swc[2];
  #pragma unroll
  for (int dgi = 0; dgi < 2; ++dgi) {
    const int d = (2 * wv + dgi) * 16 + l15;
    #pragma unroll
    for (int q = 0; q < 5; ++q) bq[dgi][q] = cb[q * 128 + d];
    swh[dgi] = selw[d]; swc[dgi] = selw[128 + d];
  }
  const float selbv = selb[0];

  // ---- pyramid: 63 sequential layers; zero global memory in the loop ----
  for (int W = 63; W >= 1; --W) {
    const int NMT = (W + 15) >> 4;
    f16x2 chP[2][4][2];     // comp_h [dgi][mt][r/2]
    f16x2 ccP[2][4][2];     // comp_c

    // ---- phase A: MFMA + gate epilogue, one mt at a time ----
    #pragma unroll
    for (int mt = 0; mt < 4; ++mt) if (mt < NMT) {
      f32x4 acc[2][5];
      #pragma unroll
      for (int dgi = 0; dgi < 2; ++dgi)
        #pragma unroll
        for (int q = 0; q < 5; ++q)
          acc[dgi][q] = (f32x4){bq[dgi][q], bq[dgi][q], bq[dgi][q], bq[dgi][q]};
      #pragma unroll
      for (int kk = 0; kk < 8; ++kk) {
        const int n   = mt * 16 + l15 + (kk >> 2);   // right half reads node n+1
        const int blk = (kk & 3) * 4 + quad;
        const f16x8 av = *(const f16x8*)&hS[n * 128 + ((blk ^ (n & 15)) << 3)];
        #pragma unroll
        for (int dgi = 0; dgi < 2; ++dgi)
          #pragma unroll
          for (int q = 0; q < 5; ++q)
            acc[dgi][q] = __builtin_amdgcn_mfma_f32_16x16x32_f16(av, Breg[kk][dgi][q], acc[dgi][q], 0, 0, 0);
      }
      const int n0q = mt * 16 + quad * 4;
      #pragma unroll
      for (int dgi = 0; dgi < 2; ++dgi) {
        const int d = (2 * wv + dgi) * 16 + l15;
        float c5[5];
        #pragma unroll
        for (int r = 0; r < 5; ++r) c5[r] = cS[(n0q + r) * 132 + d];
        #pragma unroll
        for (int r = 0; r < 4; ++r) {
          const float c = sig_(acc[dgi][1][r]) * c5[r] + sig_(acc[dgi][2][r]) * c5[r + 1]
                        + sig_(acc[dgi][0][r]) * tanh_(acc[dgi][3][r]);
          const float h = sig_(acc[dgi][4][r]) * tanh_(c);
          ccP[dgi][mt][r >> 1][r & 1] = (f16)c;
          chP[dgi][mt][r >> 1][r & 1] = (f16)h;
          float v = __builtin_fmaf(h, swh[dgi], c * swc[dgi]);   // logit partial
          v = dpp_add<0xB1, 0xF>(v);
          v = dpp_add<0x4E, 0xF>(v);
          v = dpp_add<0x124, 0xF>(v);
          v = dpp_add<0x128, 0xF>(v);
          if (l15 == 0) {
            const int n = n0q + r;
            if (n < W) lgp[((2 * wv + dgi) << 6) + n] = v;
          }
        }
      }
    }
    __syncthreads();

    // ---- phase B: softmax + prefix sums, redundantly per wave ----
    {
      float lg = -3.0e38f;
      if (lane < W) {
        float s = selbv;
        #pragma unroll
        for (int dg = 0; dg < 8; ++dg) s += lgp[(dg << 6) + lane];
        lg = s;
      }
      float m = lg;
      m = dpp_max<0xB1>(m); m = dpp_max<0x4E>(m);
      m = dpp_max<0x124>(m); m = dpp_max<0x128>(m);
      m = fmaxf(m, __shfl_xor(m, 16, 64));
      m = fmaxf(m, __shfl_xor(m, 32, 64));
      const float e = (lane < W) ? __expf(lg - m) : 0.f;
      float t = e;
      t = dpp_add<0xB1, 0xF>(t); t = dpp_add<0x4E, 0xF>(t);
      t = dpp_add<0x124, 0xF>(t); t = dpp_add<0x128, 0xF>(t);
      t += __shfl_xor(t, 16, 64);
      t += __shfl_xor(t, 32, 64);
      const float p = e / t;
      float cs = p;                       // inclusive scan (DPP)
      cs = dpp_add<0x111, 0xF>(cs);
      cs = dpp_add<0x112, 0xF>(cs);
      cs = dpp_add<0x114, 0xF>(cs);
      cs = dpp_add<0x118, 0xF>(cs);
      cs = dpp_add<0x142, 0xA>(cs);
      cs = dpp_add<0x143, 0xC>(cs);
      const float T = __shfl(cs, 63, 64);
      if (lane < W) {
        pS[lane]  = p;
        clS[lane] = T - cs;
        crS[lane] = cs - p;
      }
    }
    // (no barrier: each wave wrote its own redundant copy)

    // ---- phase C: blend; read-all-then-write-all per (mt,dgi) ----
    #pragma unroll
    for (int mt = 0; mt < 4; ++mt) if (mt < NMT) {
      const int n0q = mt * 16 + quad * 4;
      const f32x4 pv  = *(const f32x4*)&pS[n0q];
      const f32x4 clv = *(const f32x4*)&clS[n0q];
      const f32x4 crv = *(const f32x4*)&crS[n0q];
      #pragma unroll
      for (int dgi = 0; dgi < 2; ++dgi) {
        const int d = (2 * wv + dgi) * 16 + l15;
        float oh[5], c5[5];
        #pragma unroll
        for (int r = 0; r < 5; ++r) {
          oh[r] = (float)hS[hOff(n0q + r, d)];
          c5[r] = cS[(n0q + r) * 132 + d];
        }
        #pragma unroll
        for (int r = 0; r < 4; ++r) {
          const int n = n0q + r;
          if (n < W) {
            const float nh = clv[r] * oh[r] + crv[r] * oh[r + 1] + pv[r] * (float)chP[dgi][mt][r >> 1][r & 1];
            const float nc = clv[r] * c5[r] + crv[r] * c5[r + 1] + pv[r] * (float)ccP[dgi][mt][r >> 1][r & 1];
            hS[hOff(n, d)] = (f16)nh;
            cS[n * 132 + d] = nc;
          }
        }
      }
    }
    __syncthreads();
  }

  // ---- write final state[0] TRANSPOSED: finT[k][b], k in [0,256) ----
  if (tid < 128) {
    finT[tid * 64 + b]         = (float)hS[tid];   // h half (hOff(0,f)=f)
    finT[(128 + tid) * 64 + b] = cS[tid];          // c half
  }
}

// ---- MLP head: column-split, activations coalesced over rows ----
// z0: grid 64 col-tiles x block 1024 (64 rows x 16 cols)
__global__ __launch_bounds__(1024) void z0_kernel(
    const float* __restrict__ finT, const float* __restrict__ w0,
    const float* __restrict__ b0, float* __restrict__ z0T)
{
  const int t = threadIdx.x;
  const int row = t & 63, colg = t >> 6;
  const int col = blockIdx.x * 16 + colg;
  float a[4] = {0.f, 0.f, 0.f, 0.f};
  #pragma unroll 16
  for (int k = 0; k < 256; ++k)
    a[k & 3] = __builtin_fmaf(finT[k * 64 + row], w0[k * 1024 + col], a[k & 3]);
  const float z = (a[0] + a[1]) + (a[2] + a[3]) + b0[col];
  z0T[col * 64 + row] = fmaxf(z, 0.f);
}

// z1: grid 64 col-tiles x block 1024
__global__ __launch_bounds__(1024) void z1_kernel(
    const float* __restrict__ z0T, const float* __restrict__ w1,
    const float* __restrict__ b1, float* __restrict__ z1T)
{
  const int t = threadIdx.x;
  const int row = t & 63, colg = t >> 6;
  const int col = blockIdx.x * 16 + colg;
  float a[4] = {0.f, 0.f, 0.f, 0.f};
  #pragma unroll 16
  for (int k = 0; k < 1024; ++k)
    a[k & 3] = __builtin_fmaf(z0T[k * 64 + row], w1[k * 1024 + col], a[k & 3]);
  const float z = (a[0] + a[1]) + (a[2] + a[3]) + b1[col];
  z1T[col * 64 + row] = fmaxf(z, 0.f);
}

__global__ __launch_bounds__(192) void out_kernel(
    const float* __restrict__ z1T, const float* __restrict__ cwt,
    const float* __restrict__ cbias, float* __restrict__ out)
{
  const int t = threadIdx.x;            // 192 = 3 cls x 64 rows
  const int row = t & 63, cls = t >> 6;
  float a[4] = {0.f, 0.f, 0.f, 0.f};
  #pragma unroll 16
  for (int k = 0; k < 1024; ++k)
    a[k & 3] = __builtin_fmaf(z1T[k * 64 + row], cwt[k * 3 + cls], a[k & 3]);
  out[row * 3 + cls] = (a[0] + a[1]) + (a[2] + a[3]) + cbias[cls];
}

extern "C" void kernel_launch(void* const* d_in, const int* in_sizes, int n_in,
                              void* d_out, int out_size, void* d_ws, size_t ws_size,
                              hipStream_t stream) {
  (void)in_sizes; (void)n_in; (void)out_size; (void)ws_size;
  f16*   wsB  = (f16*)d_ws;                              // 409600 B
  float* finT = (float*)((char*)d_ws + 409600);          // 65536 B
  float* z0T  = (float*)((char*)d_ws + 475136);          // 262144 B
  float* z1T  = (float*)((char*)d_ws + 737280);          // 262144 B

  prep_kernel<<<dim3(80), dim3(256), 0, stream>>>((const float*)d_in[3], wsB);
  pyramid_kernel<<<dim3(64), dim3(256), 0, stream>>>(
      (const int*)d_in[0], (const float*)d_in[2], wsB,
      (const float*)d_in[4], (const float*)d_in[5], (const float*)d_in[6], finT);
  z0_kernel<<<dim3(64), dim3(1024), 0, stream>>>(
      finT, (const float*)d_in[7], (const float*)d_in[8], z0T);
  z1_kernel<<<dim3(64), dim3(1024), 0, stream>>>(
      z0T, (const float*)d_in[9], (const float*)d_in[10], z1T);
  out_kernel<<<dim3(1), dim3(192), 0, stream>>>(
      z1T, (const float*)d_in[11], (const float*)d_in[12], (float*)d_out);
}

// Round 9
// 710.570 us; speedup vs baseline: 1.5394x; 1.5394x over previous
//
#include <hip/hip_runtime.h>

#define SEQ 64

typedef _Float16 f16;
typedef _Float16 f16x8 __attribute__((ext_vector_type(8)));
typedef float f32x4 __attribute__((ext_vector_type(4)));

__device__ __forceinline__ float sig_(float x) { return 1.0f / (1.0f + __expf(-x)); }
__device__ __forceinline__ float tanh_(float x) { return 1.0f - 2.0f / (1.0f + __expf(2.0f * x)); }

template<int CTRL, int RMASK>
__device__ __forceinline__ float dpp_add(float x) {
  const int t = __builtin_amdgcn_update_dpp(0, __float_as_int(x), CTRL, RMASK, 0xF, true);
  return x + __int_as_float(t);
}
template<int CTRL>
__device__ __forceinline__ float dpp_max(float x) {
  const int t = __builtin_amdgcn_update_dpp(0, __float_as_int(x), CTRL, 0xF, 0xF, true);
  return fmaxf(x, __int_as_float(t));
}

// h state: node-major, 128 f16/row, XOR-swizzled in 8-f16 (16B) blocks
__device__ __forceinline__ int hOff(int n, int f) {
  return n * 128 + ((((f >> 3) ^ (n & 15)) << 3) | (f & 7));
}

// ---- prep: comp_W (256x640 fp32) -> f16 MFMA B-fragment order in ws ----
__global__ void prep_kernel(const float* __restrict__ cW, f16* __restrict__ wsB) {
  const int idx  = blockIdx.x * 256 + threadIdx.x;   // 0..20479
  const int kk   = idx / 2560;
  const int rem  = idx - kk * 2560;
  const int nt   = rem >> 6;
  const int lane = rem & 63;
  const int col  = nt * 16 + (lane & 15);
  const int kb   = kk * 32 + ((lane >> 4) << 3);
  f16x8 v;
  #pragma unroll
  for (int j = 0; j < 8; ++j) v[j] = (f16)cW[(kb + j) * 640 + col];
  ((f16x8*)wsB)[idx] = v;
}

// Dynamic-LDS partition (148.5 KiB total; 1 block/CU, 160 KiB available)
#define BLDS_OFF 0              // 12 B-frag sets: 12*512*16 = 98304
#define CS_OFF   98304          // c state f32: 65*132*4 = 34320
#define HS_OFF   132624         // h state f16 swizzled: 65*128*2 = 16640
#define LGP_OFF  149264         // logit partials: 8*64*4 = 2048
#define PS_OFF   151312         // p: 64*4
#define CLS_OFF  151568         // copy_left: 64*4
#define CRS_OFF  151824         // copy_right: 64*4
#define DYN_LDS  152080

// ---- pyramid: 512 threads, 2 waves/SIMD; B split 28 reg-frags + 12 LDS sets ----
__global__ __launch_bounds__(512, 2) void pyramid_kernel(
    const int*   __restrict__ sentences,
    const float* __restrict__ emb,
    const f16*   __restrict__ wsB,
    const float* __restrict__ cb, const float* __restrict__ selw, const float* __restrict__ selb,
    float* __restrict__ finT)
{
  extern __shared__ __align__(16) char dyn[];
  f16x8* Blds = (f16x8*)(dyn + BLDS_OFF);
  float* cS   = (float*)(dyn + CS_OFF);
  f16*   hS   = (f16*)  (dyn + HS_OFF);
  float* lgp  = (float*)(dyn + LGP_OFF);
  float* pS   = (float*)(dyn + PS_OFF);
  float* clS  = (float*)(dyn + CLS_OFF);
  float* crS  = (float*)(dyn + CRS_OFF);

  const int tid  = threadIdx.x;
  const int b    = blockIdx.x;
  const int wv   = tid >> 6;
  const int lane = tid & 63;
  const int quad = lane >> 4;
  const int l15  = lane & 15;
  const int d    = wv * 16 + l15;
  const f16x8* Bf = (const f16x8*)wsB;

  // ---- persistent B in regs: q=0..2 all kk (24) + q=3,kk=0..3 (4) = 112 VGPRs ----
  f16x8 Breg[28];
  #pragma unroll
  for (int kk = 0; kk < 8; ++kk)
    #pragma unroll
    for (int q = 0; q < 3; ++q)
      Breg[kk * 3 + q] = Bf[((kk * 40 + q * 8 + wv) << 6) + lane];
  #pragma unroll
  for (int kk = 0; kk < 4; ++kk)
    Breg[24 + kk] = Bf[((kk * 40 + 3 * 8 + wv) << 6) + lane];

  // ---- B in LDS: s<4 -> (kk=4+s, q=3); s>=4 -> (kk=s-4, q=4) ----
  #pragma unroll
  for (int s = 0; s < 12; ++s) {
    const int kk = (s < 4) ? (4 + s) : (s - 4);
    const int q  = (s < 4) ? 3 : 4;
    Blds[s * 512 + tid] = Bf[((kk * 40 + q * 8 + wv) << 6) + lane];
  }

  // ---- embedding gather: h -> LDS f16, c -> LDS f32 ----
  {
    const int s = tid >> 3, part = tid & 7;
    const int row = sentences[b * SEQ + s];
    const float4* er = (const float4*)(emb + (size_t)row * 256 + part * 32);
    #pragma unroll
    for (int i4 = 0; i4 < 8; ++i4) {
      const float4 v = er[i4];
      const float vv[4] = {v.x, v.y, v.z, v.w};
      #pragma unroll
      for (int c = 0; c < 4; ++c) {
        const int f = part * 32 + i4 * 4 + c;
        if (f < 128) hS[hOff(s, f)] = (f16)vv[c];
        else         cS[s * 132 + (f - 128)] = vv[c];
      }
    }
  }
  if (tid < 128) hS[64 * 128 + tid] = (f16)0.f;   // guard row (node 64)
  if (tid < 132) cS[64 * 132 + tid] = 0.f;
  __syncthreads();

  float bq[5];
  #pragma unroll
  for (int q = 0; q < 5; ++q) bq[q] = cb[q * 128 + d];
  const float swh = selw[d], swc = selw[128 + d], selbv = selb[0];

  // ---- pyramid: 63 sequential layers; zero global memory in the loop ----
  for (int W = 63; W >= 1; --W) {
    const int NMT = (W + 15) >> 4;
    float chF[4][4], ccF[4][4];

    // ---- phase A: MFMA + gate epilogue, one mt at a time ----
    #pragma unroll
    for (int mt = 0; mt < 4; ++mt) if (mt < NMT) {
      f32x4 acc[5];
      #pragma unroll
      for (int q = 0; q < 5; ++q) acc[q] = (f32x4){bq[q], bq[q], bq[q], bq[q]};
      #pragma unroll
      for (int kk = 0; kk < 8; ++kk) {
        const int n   = mt * 16 + l15 + (kk >> 2);   // right half reads node n+1
        const int blk = (kk & 3) * 4 + quad;
        const f16x8 av = *(const f16x8*)&hS[n * 128 + ((blk ^ (n & 15)) << 3)];
        #pragma unroll
        for (int q = 0; q < 3; ++q)
          acc[q] = __builtin_amdgcn_mfma_f32_16x16x32_f16(av, Breg[kk * 3 + q], acc[q], 0, 0, 0);
        const f16x8 b3 = (kk < 4) ? Breg[24 + kk] : Blds[(kk - 4) * 512 + tid];
        acc[3] = __builtin_amdgcn_mfma_f32_16x16x32_f16(av, b3, acc[3], 0, 0, 0);
        const f16x8 b4 = Blds[(4 + kk) * 512 + tid];
        acc[4] = __builtin_amdgcn_mfma_f32_16x16x32_f16(av, b4, acc[4], 0, 0, 0);
      }
      const int n0q = mt * 16 + quad * 4;
      float c5[5];
      #pragma unroll
      for (int r = 0; r < 5; ++r) c5[r] = cS[(n0q + r) * 132 + d];
      #pragma unroll
      for (int r = 0; r < 4; ++r) {
        const float c = sig_(acc[1][r]) * c5[r] + sig_(acc[2][r]) * c5[r + 1]
                      + sig_(acc[0][r]) * tanh_(acc[3][r]);
        const float h = sig_(acc[4][r]) * tanh_(c);
        ccF[mt][r] = c; chF[mt][r] = h;
        float v = __builtin_fmaf(h, swh, c * swc);   // logit partial
        v = dpp_add<0xB1, 0xF>(v);
        v = dpp_add<0x4E, 0xF>(v);
        v = dpp_add<0x124, 0xF>(v);
        v = dpp_add<0x128, 0xF>(v);
        if (l15 == 0) {
          const int n = n0q + r;
          if (n < W) lgp[(wv << 6) + n] = v;
        }
      }
    }
    __syncthreads();

    // ---- phase B: softmax + prefix sums, redundantly per wave ----
    {
      float lg = -3.0e38f;
      if (lane < W) {
        float s = selbv;
        #pragma unroll
        for (int dg = 0; dg < 8; ++dg) s += lgp[(dg << 6) + lane];
        lg = s;
      }
      float m = lg;
      m = dpp_max<0xB1>(m); m = dpp_max<0x4E>(m);
      m = dpp_max<0x124>(m); m = dpp_max<0x128>(m);
      m = fmaxf(m, __shfl_xor(m, 16, 64));
      m = fmaxf(m, __shfl_xor(m, 32, 64));
      const float e = (lane < W) ? __expf(lg - m) : 0.f;
      float t = e;
      t = dpp_add<0xB1, 0xF>(t); t = dpp_add<0x4E, 0xF>(t);
      t = dpp_add<0x124, 0xF>(t); t = dpp_add<0x128, 0xF>(t);
      t += __shfl_xor(t, 16, 64);
      t += __shfl_xor(t, 32, 64);
      const float p = e / t;
      float cs = p;                       // inclusive scan (DPP)
      cs = dpp_add<0x111, 0xF>(cs);
      cs = dpp_add<0x112, 0xF>(cs);
      cs = dpp_add<0x114, 0xF>(cs);
      cs = dpp_add<0x118, 0xF>(cs);
      cs = dpp_add<0x142, 0xA>(cs);
      cs = dpp_add<0x143, 0xC>(cs);
      const float T = __shfl(cs, 63, 64);
      if (lane < W) {
        pS[lane]  = p;
        clS[lane] = T - cs;
        crS[lane] = cs - p;
      }
    }
    // (no barrier: each wave wrote its own redundant copy)

    // ---- phase C: blend; read-all-then-write-all per mt ----
    #pragma unroll
    for (int mt = 0; mt < 4; ++mt) if (mt < NMT) {
      const int n0q = mt * 16 + quad * 4;
      const f32x4 pv  = *(const f32x4*)&pS[n0q];
      const f32x4 clv = *(const f32x4*)&clS[n0q];
      const f32x4 crv = *(const f32x4*)&crS[n0q];
      float oh[5], c5[5];
      #pragma unroll
      for (int r = 0; r < 5; ++r) {
        oh[r] = (float)hS[hOff(n0q + r, d)];
        c5[r] = cS[(n0q + r) * 132 + d];
      }
      #pragma unroll
      for (int r = 0; r < 4; ++r) {
        const int n = n0q + r;
        if (n < W) {
          const float nh = clv[r] * oh[r] + crv[r] * oh[r + 1] + pv[r] * chF[mt][r];
          const float nc = clv[r] * c5[r] + crv[r] * c5[r + 1] + pv[r] * ccF[mt][r];
          hS[hOff(n, d)] = (f16)nh;
          cS[n * 132 + d] = nc;
        }
      }
    }
    __syncthreads();
  }

  // ---- write final state[0] TRANSPOSED: finT[k][b] ----
  if (tid < 128) {
    finT[tid * 64 + b]         = (float)hS[tid];   // hOff(0,f)=f
    finT[(128 + tid) * 64 + b] = cS[tid];          // cS row 0
  }
}

// ---- MLP head: col-tile kernels, weights read once, fully coalesced ----
// z0: grid 16 (64-col tiles), block 1024 = 64 cols x 16 row-groups(4 rows)
__global__ __launch_bounds__(1024) void z0_kernel(
    const float* __restrict__ finT, const float* __restrict__ w0,
    const float* __restrict__ b0, float* __restrict__ z0T)
{
  __shared__ float zl[128 * 64];   // 32 KB k-chunk of activations
  const int t    = threadIdx.x;
  const int col  = blockIdx.x * 64 + (t & 63);
  const int rowg = t >> 6;
  float a[4] = {0.f, 0.f, 0.f, 0.f};
  for (int k0 = 0; k0 < 256; k0 += 128) {
    __syncthreads();
    #pragma unroll
    for (int i = 0; i < 8; ++i) zl[t + i * 1024] = finT[k0 * 64 + t + i * 1024];
    __syncthreads();
    #pragma unroll 4
    for (int kc = 0; kc < 128; ++kc) {
      const float w = w0[(k0 + kc) * 1024 + col];        // 64-lane coalesced
      const f32x4 z = *(const f32x4*)&zl[kc * 64 + rowg * 4];  // LDS broadcast
      #pragma unroll
      for (int j = 0; j < 4; ++j) a[j] = __builtin_fmaf(z[j], w, a[j]);
    }
  }
  const float bias = b0[col];
  #pragma unroll
  for (int j = 0; j < 4; ++j)
    z0T[col * 64 + rowg * 4 + j] = fmaxf(a[j] + bias, 0.f);
}

// z1: grid 16, block 1024; k=1024 in 8 chunks of 128
__global__ __launch_bounds__(1024) void z1_kernel(
    const float* __restrict__ z0T, const float* __restrict__ w1,
    const float* __restrict__ b1, float* __restrict__ z1T)
{
  __shared__ float zl[128 * 64];
  const int t    = threadIdx.x;
  const int col  = blockIdx.x * 64 + (t & 63);
  const int rowg = t >> 6;
  float a[4] = {0.f, 0.f, 0.f, 0.f};
  for (int k0 = 0; k0 < 1024; k0 += 128) {
    __syncthreads();
    #pragma unroll
    for (int i = 0; i < 8; ++i) zl[t + i * 1024] = z0T[k0 * 64 + t + i * 1024];
    __syncthreads();
    #pragma unroll 4
    for (int kc = 0; kc < 128; ++kc) {
      const float w = w1[(k0 + kc) * 1024 + col];
      const f32x4 z = *(const f32x4*)&zl[kc * 64 + rowg * 4];
      #pragma unroll
      for (int j = 0; j < 4; ++j) a[j] = __builtin_fmaf(z[j], w, a[j]);
    }
  }
  const float bias = b1[col];
  #pragma unroll
  for (int j = 0; j < 4; ++j)
    z1T[col * 64 + rowg * 4 + j] = fmaxf(a[j] + bias, 0.f);
}

__global__ __launch_bounds__(192) void out_kernel(
    const float* __restrict__ z1T, const float* __restrict__ cwt,
    const float* __restrict__ cbias, float* __restrict__ out)
{
  const int t = threadIdx.x;            // 192 = 3 cls x 64 rows
  const int row = t & 63, cls = t >> 6;
  float a[4] = {0.f, 0.f, 0.f, 0.f};
  #pragma unroll 16
  for (int k = 0; k < 1024; ++k)
    a[k & 3] = __builtin_fmaf(z1T[k * 64 + row], cwt[k * 3 + cls], a[k & 3]);
  out[row * 3 + cls] = (a[0] + a[1]) + (a[2] + a[3]) + cbias[cls];
}

extern "C" void kernel_launch(void* const* d_in, const int* in_sizes, int n_in,
                              void* d_out, int out_size, void* d_ws, size_t ws_size,
                              hipStream_t stream) {
  (void)in_sizes; (void)n_in; (void)out_size; (void)ws_size;
  f16*   wsB  = (f16*)d_ws;                              // 409600 B
  float* finT = (float*)((char*)d_ws + 409600);          // 65536 B
  float* z0T  = (float*)((char*)d_ws + 475136);          // 262144 B
  float* z1T  = (float*)((char*)d_ws + 737280);          // 262144 B

  // allow >64 KB dynamic LDS (160 KiB/CU on gfx950); host-state call, not enqueued
  (void)hipFuncSetAttribute((const void*)pyramid_kernel,
                            hipFuncAttributeMaxDynamicSharedMemorySize, DYN_LDS);

  prep_kernel<<<dim3(80), dim3(256), 0, stream>>>((const float*)d_in[3], wsB);
  pyramid_kernel<<<dim3(64), dim3(512), DYN_LDS, stream>>>(
      (const int*)d_in[0], (const float*)d_in[2], wsB,
      (const float*)d_in[4], (const float*)d_in[5], (const float*)d_in[6], finT);
  z0_kernel<<<dim3(16), dim3(1024), 0, stream>>>(
      finT, (const float*)d_in[7], (const float*)d_in[8], z0T);
  z1_kernel<<<dim3(16), dim3(1024), 0, stream>>>(
      z0T, (const float*)d_in[9], (const float*)d_in[10], z1T);
  out_kernel<<<dim3(1), dim3(192), 0, stream>>>(
      z1T, (const float*)d_in[11], (const float*)d_in[12], (float*)d_out);
}

// Round 10
// 654.124 us; speedup vs baseline: 1.6723x; 1.0863x over previous
//
#include <hip/hip_runtime.h>

#define SEQ 64

typedef _Float16 f16;
typedef _Float16 f16x8 __attribute__((ext_vector_type(8)));
typedef float f32x4 __attribute__((ext_vector_type(4)));

__device__ __forceinline__ float sig_(float x) { return 1.0f / (1.0f + __expf(-x)); }
__device__ __forceinline__ float tanh_(float x) { return 1.0f - 2.0f / (1.0f + __expf(2.0f * x)); }

template<int CTRL, int RMASK>
__device__ __forceinline__ float dpp_add(float x) {
  const int t = __builtin_amdgcn_update_dpp(0, __float_as_int(x), CTRL, RMASK, 0xF, true);
  return x + __int_as_float(t);
}
template<int CTRL>
__device__ __forceinline__ float dpp_max(float x) {
  const int t = __builtin_amdgcn_update_dpp(0, __float_as_int(x), CTRL, 0xF, 0xF, true);
  return fmaxf(x, __int_as_float(t));
}

// h state: node-major, 128 f16/row, XOR-swizzled in 8-f16 (16B) blocks
__device__ __forceinline__ int hOff(int n, int f) {
  return n * 128 + ((((f >> 3) ^ (n & 15)) << 3) | (f & 7));
}

// ---- prep: comp_W (256x640 fp32) -> f16 MFMA B-fragment order in ws ----
__global__ void prep_kernel(const float* __restrict__ cW, f16* __restrict__ wsB) {
  const int idx  = blockIdx.x * 256 + threadIdx.x;   // 0..20479
  const int kk   = idx / 2560;
  const int rem  = idx - kk * 2560;
  const int nt   = rem >> 6;
  const int lane = rem & 63;
  const int col  = nt * 16 + (lane & 15);
  const int kb   = kk * 32 + ((lane >> 4) << 3);
  f16x8 v;
  #pragma unroll
  for (int j = 0; j < 8; ++j) v[j] = (f16)cW[(kb + j) * 640 + col];
  ((f16x8*)wsB)[idx] = v;
}

// Dynamic-LDS partition (148.5 KiB total; 1 block/CU, 160 KiB available)
#define BLDS_OFF 0              // 12 B-frag sets: 12*512*16 = 98304
#define CS_OFF   98304          // c state f32: 65*132*4 = 34320
#define HS_OFF   132624         // h state f16 swizzled: 65*128*2 = 16640
#define LGP_OFF  149264         // logit partials: 8*64*4 = 2048
#define PS_OFF   151312         // p: 64*4
#define CLS_OFF  151568         // copy_left: 64*4
#define CRS_OFF  151824         // copy_right: 64*4
#define DYN_LDS  152080

// ---- pyramid: 512 threads; __launch_bounds__(512,1) => 1 block/CU,
// 8 waves, 256 regs/wave. (The 2nd arg behaves as CUDA min-blocks/CU:
// (512,2) demonstrably capped VGPR_Count at 128 in rounds 3-6,9.) ----
__global__ __launch_bounds__(512, 1) void pyramid_kernel(
    const int*   __restrict__ sentences,
    const float* __restrict__ emb,
    const f16*   __restrict__ wsB,
    const float* __restrict__ cb, const float* __restrict__ selw, const float* __restrict__ selb,
    float* __restrict__ finT)
{
  extern __shared__ __align__(16) char dyn[];
  f16x8* Blds = (f16x8*)(dyn + BLDS_OFF);
  float* cS   = (float*)(dyn + CS_OFF);
  f16*   hS   = (f16*)  (dyn + HS_OFF);
  float* lgp  = (float*)(dyn + LGP_OFF);
  float* pS   = (float*)(dyn + PS_OFF);
  float* clS  = (float*)(dyn + CLS_OFF);
  float* crS  = (float*)(dyn + CRS_OFF);

  const int tid  = threadIdx.x;
  const int b    = blockIdx.x;
  const int wv   = tid >> 6;
  const int lane = tid & 63;
  const int quad = lane >> 4;
  const int l15  = lane & 15;
  const int d    = wv * 16 + l15;
  const f16x8* Bf = (const f16x8*)wsB;

  // ---- persistent B in regs: q=0..2 all kk (24) + q=3,kk=0..3 (4) = 112 VGPRs ----
  f16x8 Breg[28];
  #pragma unroll
  for (int kk = 0; kk < 8; ++kk)
    #pragma unroll
    for (int q = 0; q < 3; ++q)
      Breg[kk * 3 + q] = Bf[((kk * 40 + q * 8 + wv) << 6) + lane];
  #pragma unroll
  for (int kk = 0; kk < 4; ++kk)
    Breg[24 + kk] = Bf[((kk * 40 + 3 * 8 + wv) << 6) + lane];

  // ---- B in LDS: s<4 -> (kk=4+s, q=3); s>=4 -> (kk=s-4, q=4) ----
  #pragma unroll
  for (int s = 0; s < 12; ++s) {
    const int kk = (s < 4) ? (4 + s) : (s - 4);
    const int q  = (s < 4) ? 3 : 4;
    Blds[s * 512 + tid] = Bf[((kk * 40 + q * 8 + wv) << 6) + lane];
  }

  // ---- embedding gather: h -> LDS f16, c -> LDS f32 ----
  {
    const int s = tid >> 3, part = tid & 7;
    const int row = sentences[b * SEQ + s];
    const float4* er = (const float4*)(emb + (size_t)row * 256 + part * 32);
    #pragma unroll
    for (int i4 = 0; i4 < 8; ++i4) {
      const float4 v = er[i4];
      const float vv[4] = {v.x, v.y, v.z, v.w};
      #pragma unroll
      for (int c = 0; c < 4; ++c) {
        const int f = part * 32 + i4 * 4 + c;
        if (f < 128) hS[hOff(s, f)] = (f16)vv[c];
        else         cS[s * 132 + (f - 128)] = vv[c];
      }
    }
  }
  if (tid < 128) hS[64 * 128 + tid] = (f16)0.f;   // guard row (node 64)
  if (tid < 132) cS[64 * 132 + tid] = 0.f;
  __syncthreads();

  float bq[5];
  #pragma unroll
  for (int q = 0; q < 5; ++q) bq[q] = cb[q * 128 + d];
  const float swh = selw[d], swc = selw[128 + d], selbv = selb[0];

  // ---- pyramid: 63 sequential layers; zero global memory in the loop ----
  for (int W = 63; W >= 1; --W) {
    const int NMT = (W + 15) >> 4;
    float chF[4][4], ccF[4][4];

    // ---- phase A: MFMA + gate epilogue, one mt at a time ----
    #pragma unroll
    for (int mt = 0; mt < 4; ++mt) if (mt < NMT) {
      f32x4 acc[5];
      #pragma unroll
      for (int q = 0; q < 5; ++q) acc[q] = (f32x4){bq[q], bq[q], bq[q], bq[q]};
      #pragma unroll
      for (int kk = 0; kk < 8; ++kk) {
        const int n   = mt * 16 + l15 + (kk >> 2);   // right half reads node n+1
        const int blk = (kk & 3) * 4 + quad;
        const f16x8 av = *(const f16x8*)&hS[n * 128 + ((blk ^ (n & 15)) << 3)];
        #pragma unroll
        for (int q = 0; q < 3; ++q)
          acc[q] = __builtin_amdgcn_mfma_f32_16x16x32_f16(av, Breg[kk * 3 + q], acc[q], 0, 0, 0);
        const f16x8 b3 = (kk < 4) ? Breg[24 + kk] : Blds[(kk - 4) * 512 + tid];
        acc[3] = __builtin_amdgcn_mfma_f32_16x16x32_f16(av, b3, acc[3], 0, 0, 0);
        const f16x8 b4 = Blds[(4 + kk) * 512 + tid];
        acc[4] = __builtin_amdgcn_mfma_f32_16x16x32_f16(av, b4, acc[4], 0, 0, 0);
      }
      const int n0q = mt * 16 + quad * 4;
      float c5[5];
      #pragma unroll
      for (int r = 0; r < 5; ++r) c5[r] = cS[(n0q + r) * 132 + d];
      #pragma unroll
      for (int r = 0; r < 4; ++r) {
        const float c = sig_(acc[1][r]) * c5[r] + sig_(acc[2][r]) * c5[r + 1]
                      + sig_(acc[0][r]) * tanh_(acc[3][r]);
        const float h = sig_(acc[4][r]) * tanh_(c);
        ccF[mt][r] = c; chF[mt][r] = h;
        float v = __builtin_fmaf(h, swh, c * swc);   // logit partial
        v = dpp_add<0xB1, 0xF>(v);
        v = dpp_add<0x4E, 0xF>(v);
        v = dpp_add<0x124, 0xF>(v);
        v = dpp_add<0x128, 0xF>(v);
        if (l15 == 0) {
          const int n = n0q + r;
          if (n < W) lgp[(wv << 6) + n] = v;
        }
      }
    }
    __syncthreads();

    // ---- phase B: softmax + prefix sums, redundantly per wave ----
    {
      float lg = -3.0e38f;
      if (lane < W) {
        float s = selbv;
        #pragma unroll
        for (int dg = 0; dg < 8; ++dg) s += lgp[(dg << 6) + lane];
        lg = s;
      }
      float m = lg;
      m = dpp_max<0xB1>(m); m = dpp_max<0x4E>(m);
      m = dpp_max<0x124>(m); m = dpp_max<0x128>(m);
      m = fmaxf(m, __shfl_xor(m, 16, 64));
      m = fmaxf(m, __shfl_xor(m, 32, 64));
      const float e = (lane < W) ? __expf(lg - m) : 0.f;
      float t = e;
      t = dpp_add<0xB1, 0xF>(t); t = dpp_add<0x4E, 0xF>(t);
      t = dpp_add<0x124, 0xF>(t); t = dpp_add<0x128, 0xF>(t);
      t += __shfl_xor(t, 16, 64);
      t += __shfl_xor(t, 32, 64);
      const float p = e / t;
      float cs = p;                       // inclusive scan (DPP)
      cs = dpp_add<0x111, 0xF>(cs);
      cs = dpp_add<0x112, 0xF>(cs);
      cs = dpp_add<0x114, 0xF>(cs);
      cs = dpp_add<0x118, 0xF>(cs);
      cs = dpp_add<0x142, 0xA>(cs);
      cs = dpp_add<0x143, 0xC>(cs);
      const float T = __shfl(cs, 63, 64);
      if (lane < W) {
        pS[lane]  = p;
        clS[lane] = T - cs;
        crS[lane] = cs - p;
      }
    }
    // (no barrier: each wave wrote its own redundant copy)

    // ---- phase C: blend; read-all-then-write-all per mt ----
    #pragma unroll
    for (int mt = 0; mt < 4; ++mt) if (mt < NMT) {
      const int n0q = mt * 16 + quad * 4;
      const f32x4 pv  = *(const f32x4*)&pS[n0q];
      const f32x4 clv = *(const f32x4*)&clS[n0q];
      const f32x4 crv = *(const f32x4*)&crS[n0q];
      float oh[5], c5[5];
      #pragma unroll
      for (int r = 0; r < 5; ++r) {
        oh[r] = (float)hS[hOff(n0q + r, d)];
        c5[r] = cS[(n0q + r) * 132 + d];
      }
      #pragma unroll
      for (int r = 0; r < 4; ++r) {
        const int n = n0q + r;
        if (n < W) {
          const float nh = clv[r] * oh[r] + crv[r] * oh[r + 1] + pv[r] * chF[mt][r];
          const float nc = clv[r] * c5[r] + crv[r] * c5[r + 1] + pv[r] * ccF[mt][r];
          hS[hOff(n, d)] = (f16)nh;
          cS[n * 132 + d] = nc;
        }
      }
    }
    __syncthreads();
  }

  // ---- write final state[0] TRANSPOSED: finT[k][b] ----
  if (tid < 128) {
    finT[tid * 64 + b]         = (float)hS[tid];   // hOff(0,f)=f
    finT[(128 + tid) * 64 + b] = cS[tid];          // cS row 0
  }
}

// ---- MLP head (fp32) ----
// z0: grid 64 blocks x 512 thr; block = 16 cols (2 per wave), row = lane.
// X (finT, 64 KB) staged whole in LDS; w0 reads wave-uniform broadcast.
__global__ __launch_bounds__(512) void z0_kernel(
    const float* __restrict__ finT, const float* __restrict__ w0,
    const float* __restrict__ b0, float* __restrict__ z0T)
{
  __shared__ float XL[256 * 64];   // 64 KB
  const int t    = threadIdx.x;
  const int lane = t & 63;         // row
  const int wvq  = t >> 6;         // 8 waves
  const int c0   = blockIdx.x * 16 + wvq * 2;
  #pragma unroll
  for (int i = 0; i < 32; ++i) XL[t + i * 512] = finT[t + i * 512];
  __syncthreads();
  float a0 = 0.f, a1 = 0.f;
  #pragma unroll 8
  for (int k = 0; k < 256; ++k) {
    const float x  = XL[k * 64 + lane];
    const float2 w = *(const float2*)&w0[k * 1024 + c0];
    a0 = __builtin_fmaf(x, w.x, a0);
    a1 = __builtin_fmaf(x, w.y, a1);
  }
  z0T[c0 * 64 + lane]       = fmaxf(a0 + b0[c0], 0.f);
  z0T[(c0 + 1) * 64 + lane] = fmaxf(a1 + b0[c0 + 1], 0.f);
}

// z1: grid 256 blocks x 256 thr; block = 4 cols (1 per wave), row = lane.
// z0T (256 KB) chunk-staged; one output per thread.
__global__ __launch_bounds__(256) void z1_kernel(
    const float* __restrict__ z0T, const float* __restrict__ w1,
    const float* __restrict__ b1, float* __restrict__ z1T)
{
  __shared__ float ZL[128 * 64];   // 32 KB chunk
  const int t    = threadIdx.x;
  const int lane = t & 63;         // row
  const int wvq  = t >> 6;         // 4 waves
  const int col  = blockIdx.x * 4 + wvq;
  float a = 0.f;
  for (int k0 = 0; k0 < 1024; k0 += 128) {
    __syncthreads();
    #pragma unroll
    for (int i = 0; i < 32; ++i) ZL[t + i * 256] = z0T[k0 * 64 + t + i * 256];
    __syncthreads();
    #pragma unroll 8
    for (int kc = 0; kc < 128; ++kc)
      a = __builtin_fmaf(ZL[kc * 64 + lane], w1[(k0 + kc) * 1024 + col], a);
  }
  z1T[col * 64 + lane] = fmaxf(a + b1[col], 0.f);
}

__global__ __launch_bounds__(192) void out_kernel(
    const float* __restrict__ z1T, const float* __restrict__ cwt,
    const float* __restrict__ cbias, float* __restrict__ out)
{
  const int t = threadIdx.x;            // 192 = 3 cls x 64 rows
  const int row = t & 63, cls = t >> 6;
  float a[4] = {0.f, 0.f, 0.f, 0.f};
  #pragma unroll 16
  for (int k = 0; k < 1024; ++k)
    a[k & 3] = __builtin_fmaf(z1T[k * 64 + row], cwt[k * 3 + cls], a[k & 3]);
  out[row * 3 + cls] = (a[0] + a[1]) + (a[2] + a[3]) + cbias[cls];
}

extern "C" void kernel_launch(void* const* d_in, const int* in_sizes, int n_in,
                              void* d_out, int out_size, void* d_ws, size_t ws_size,
                              hipStream_t stream) {
  (void)in_sizes; (void)n_in; (void)out_size; (void)ws_size;
  f16*   wsB  = (f16*)d_ws;                              // 409600 B
  float* finT = (float*)((char*)d_ws + 409600);          // 65536 B
  float* z0T  = (float*)((char*)d_ws + 475136);          // 262144 B
  float* z1T  = (float*)((char*)d_ws + 737280);          // 262144 B

  // allow >64 KB dynamic LDS (160 KiB/CU on gfx950); host-state call, not enqueued
  (void)hipFuncSetAttribute((const void*)pyramid_kernel,
                            hipFuncAttributeMaxDynamicSharedMemorySize, DYN_LDS);

  prep_kernel<<<dim3(80), dim3(256), 0, stream>>>((const float*)d_in[3], wsB);
  pyramid_kernel<<<dim3(64), dim3(512), DYN_LDS, stream>>>(
      (const int*)d_in[0], (const float*)d_in[2], wsB,
      (const float*)d_in[4], (const float*)d_in[5], (const float*)d_in[6], finT);
  z0_kernel<<<dim3(64), dim3(512), 0, stream>>>(
      finT, (const float*)d_in[7], (const float*)d_in[8], z0T);
  z1_kernel<<<dim3(256), dim3(256), 0, stream>>>(
      z0T, (const float*)d_in[9], (const float*)d_in[10], z1T);
  out_kernel<<<dim3(1), dim3(192), 0, stream>>>(
      z1T, (const float*)d_in[11], (const float*)d_in[12], (float*)d_out);
}